// Round 2
// baseline (577.702 us; speedup 1.0000x reference)
//
#include <hip/hip_runtime.h>

// NATTEN 3D neighborhood attention — fp16 MFMA flash-style.
// B=1, T=16, H=32, W=32, nh=8, D=128, window (3,7,7), fp32 in/out.
//
// R5: query tile grown (1,4,8)->(2,4,8): 64 queries/block, 256 threads.
// Halo keys/query drops 13.1 -> 8.75 (1.5x less staging+softmax+barrier
// work per query). Halo = 4x10x14 = 560 keys, processed as 8 chunks of
// (1,5,14)=70 keys (padded to 80 for QK n-tiles, 96 for PV k-steps).
// Queries within the 2-deep T tile have distinct T-windows -> per-query
// tOK mask per chunk (dt in [aT, aT+3)).
// GEMM1: S^T[80][64] = Q[64x128] * K^T   via mfma_f32_16x16x32_f16
// GEMM2: O[64][128] += P[64x96] * V[96x128]
// All MFMA operands in LDS frag-order (lane-linear 16B slots).
// LDS ~75.6 KB -> 2 blocks/CU (8 waves/CU).

typedef _Float16 f16;
typedef _Float16 half8 __attribute__((ext_vector_type(8)));
typedef float floatx4 __attribute__((ext_vector_type(4)));

namespace {

constexpr int T = 16, H = 32, W = 32, NH = 8, D = 128;
constexpr int QT = 2, QH = 4, QW = 8;  // 64 queries/block
constexpr float SCALE = 0.088388347648318447f;  // 128^-0.5

__device__ __forceinline__ size_t goff(int tt, int hh, int ww, int head) {
  return ((size_t)((tt * H + hh) * W + ww) * NH + head) * D;
}

__global__ __launch_bounds__(256) void na3d_mfma(
    const float* __restrict__ qp, const float* __restrict__ kp,
    const float* __restrict__ vp, float* __restrict__ op) {
  // frag-order buffers: slot = ((tile*ksteps + ks)*64 + lane) * 8 f16
  __shared__ alignas(16) f16 qbuf[4 * 4 * 64 * 8];    // Q  A-frags 16384 B
  __shared__ alignas(16) f16 kvbuf[8 * 3 * 64 * 8];   // K/V B-frags 24576 B
  __shared__ alignas(16) float st[80 * 65];           // S^T [key][q] 20800 B
  __shared__ alignas(16) f16 pbuf[4 * 3 * 64 * 8];    // P  A-frags 12288 B
  __shared__ alignas(16) float red[4 * 64];           // max/sum partials
  __shared__ alignas(16) float mnew[64];              // row max (then 1/l)
  __shared__ alignas(16) float alphas[64];            // rescale factors

  int bid = blockIdx.x;
  const int wb = bid & 3;  bid >>= 2;   // W/QW = 4
  const int hb = bid & 7;  bid >>= 3;   // H/QH = 8
  const int tb = bid & 7;  bid >>= 3;   // T/QT = 8
  const int head = bid;                 // 8

  const int t0 = tb * QT;
  const int h0 = hb * QH, w0 = wb * QW;
  const int bT = min(max(t0 - 1, 0), T - 4);    // key block T start (span 4)
  const int bH = min(max(h0 - 3, 0), H - 10);
  const int bW = min(max(w0 - 3, 0), W - 14);

  const int tid = threadIdx.x;
  const int wave = tid >> 6, lane = tid & 63;
  const int quad = lane >> 4, ln = lane & 15;

  // ---- Q staging: frag-order, pre-scaled, fp32->fp16 ----
  for (int s = tid; s < 1024; s += 256) {
    const int q = s >> 4, dg = s & 15;
    const size_t off =
        goff(t0 + (q >> 5), h0 + ((q >> 3) & 3), w0 + (q & 7), head) + dg * 8;
    const float4 x0 = *(const float4*)(qp + off);
    const float4 x1 = *(const float4*)(qp + off + 4);
    half8 hv;
    hv[0] = (f16)(x0.x * SCALE); hv[1] = (f16)(x0.y * SCALE);
    hv[2] = (f16)(x0.z * SCALE); hv[3] = (f16)(x0.w * SCALE);
    hv[4] = (f16)(x1.x * SCALE); hv[5] = (f16)(x1.y * SCALE);
    hv[6] = (f16)(x1.z * SCALE); hv[7] = (f16)(x1.w * SCALE);
    const int mt = q >> 4, m = q & 15, ks = dg >> 2, qd = dg & 3;
    *(half8*)&qbuf[(((mt * 4 + ks) * 64) + qd * 16 + m) * 8] = hv;
  }

  floatx4 oacc[8] = {{0.f, 0.f, 0.f, 0.f}, {0.f, 0.f, 0.f, 0.f},
                     {0.f, 0.f, 0.f, 0.f}, {0.f, 0.f, 0.f, 0.f},
                     {0.f, 0.f, 0.f, 0.f}, {0.f, 0.f, 0.f, 0.f},
                     {0.f, 0.f, 0.f, 0.f}, {0.f, 0.f, 0.f, 0.f}};
  // GEMM2: wave owns m-tile = wave (16 queries), all 8 d-groups (u)

  float m_run = -1e30f, l_run = 0.f;  // live in tid<64 only

  // softmax thread mapping: sq = query (0..63), sp = key-partition (0..3)
  const int sq = tid & 63, sp = tid >> 6;
  const int aT = min(max(t0 + (sq >> 5) - 1, 0), T - 3) - bT;         // 0..2
  const int aH = min(max(h0 + ((sq >> 3) & 3) - 3, 0), H - 7) - bH;   // 0..3
  const int aW = min(max(w0 + (sq & 7) - 3, 0), W - 7) - bW;          // 0..7

  for (int c = 0; c < 8; ++c) {
    const int dt = c >> 1, hh = c & 1;
    const int tt = bT + dt;
    const int kh0 = bH + hh * 5;
    const bool tOK = (dt >= aT) && (dt < aT + 3);  // per-query T-window

    __syncthreads();  // protect kvbuf from prior GEMM2 reads
    // ---- K staging: frag-order (rows are contiguous dims -> 16B copies) --
    for (int s = tid; s < 1120; s += 256) {
      const int kk = s >> 4, dg = s & 15;
      const int khl = kk / 14, kw = kk - khl * 14;
      const size_t off = goff(tt, kh0 + khl, bW + kw, head) + dg * 8;
      const float4 x0 = *(const float4*)(kp + off);
      const float4 x1 = *(const float4*)(kp + off + 4);
      half8 hv;
      hv[0] = (f16)x0.x; hv[1] = (f16)x0.y; hv[2] = (f16)x0.z; hv[3] = (f16)x0.w;
      hv[4] = (f16)x1.x; hv[5] = (f16)x1.y; hv[6] = (f16)x1.z; hv[7] = (f16)x1.w;
      const int nt = kk >> 4, n = kk & 15, ks = dg >> 2, qd = dg & 3;
      *(half8*)&kvbuf[(((nt * 4 + ks) * 64) + qd * 16 + n) * 8] = hv;
    }
    __syncthreads();

    // ---- GEMM1: S^T = Q * K^T (20 tiles = 4 mt x 5 nt over 4 waves) ----
    for (int tile = wave; tile < 20; tile += 4) {
      const int mt = tile / 5, nt = tile - mt * 5;
      floatx4 acc = {0.f, 0.f, 0.f, 0.f};
#pragma unroll
      for (int ks = 0; ks < 4; ++ks) {
        const half8 a = *(const half8*)&qbuf[(((mt * 4 + ks) * 64) + lane) * 8];
        const half8 b = *(const half8*)&kvbuf[(((nt * 4 + ks) * 64) + lane) * 8];
        acc = __builtin_amdgcn_mfma_f32_16x16x32_f16(a, b, acc, 0, 0, 0);
      }
      // D layout: col(lane&15)=key-within-tile, row(quad*4+reg)=query
      float* dst = &st[(nt * 16 + ln) * 65 + mt * 16 + quad * 4];
      dst[0] = acc[0]; dst[1] = acc[1]; dst[2] = acc[2]; dst[3] = acc[3];
    }
    __syncthreads();

    // ---- softmax pass 1: chunk row max (valid window only) ----
    float pm = -1e30f;
    if (tOK) {
#pragma unroll
      for (int i = 0; i < 18; ++i) {
        const int kk = sp * 18 + i;
        if (kk < 70) {
          const int khl = kk / 14, kw = kk - khl * 14;
          const int kha = hh * 5 + khl;
          if (kha >= aH && kha < aH + 7 && kw >= aW && kw < aW + 7)
            pm = fmaxf(pm, st[kk * 65 + sq]);
        }
      }
    }
    red[sp * 64 + sq] = pm;
    __syncthreads();
    if (tid < 64) {
      float mc = red[tid];
#pragma unroll
      for (int p = 1; p < 4; ++p) mc = fmaxf(mc, red[p * 64 + tid]);
      const float mN = fmaxf(m_run, mc);
      const float a = __expf(m_run - mN);
      m_run = mN; l_run *= a;
      mnew[tid] = mN; alphas[tid] = a;
    }
    __syncthreads();

    // ---- pass 2: P = exp(S-m), frag-order f16; partial row sums ----
    const float mq = mnew[sq];
    float ps = 0.f;
#pragma unroll
    for (int i = 0; i < 24; ++i) {
      const int kk = sp * 24 + i;  // 0..95 covers all of pbuf
      f16 pv = (f16)0.f;
      if (tOK && kk < 70) {
        const int khl = kk / 14, kw = kk - khl * 14;
        const int kha = hh * 5 + khl;
        if (kha >= aH && kha < aH + 7 && kw >= aW && kw < aW + 7) {
          const float e = __expf(st[kk * 65 + sq] - mq);
          ps += e; pv = (f16)e;
        }
      }
      pbuf[((((sq >> 4) * 3 + (kk >> 5)) * 64) + ((kk >> 3) & 3) * 16 +
            (sq & 15)) * 8 + (kk & 7)] = pv;
    }
    red[sp * 64 + sq] = ps;

    // ---- V staging: transpose into B-frag order (b16 scatters) ----
    // keys 0..69 from global; keys 70..95 ZEROED (P=0 there, but MFMA would
    // still propagate NaN from uninitialized LDS: 0*NaN = NaN).
    for (int s = tid; s < 1536; s += 256) {
      const int kk = s >> 4, dg = s & 15;
      float xs[8] = {0.f, 0.f, 0.f, 0.f, 0.f, 0.f, 0.f, 0.f};
      if (kk < 70) {
        const int khl = kk / 14, kw = kk - khl * 14;
        const size_t off = goff(tt, kh0 + khl, bW + kw, head) + dg * 8;
        const float4 x0 = *(const float4*)(vp + off);
        const float4 x1 = *(const float4*)(vp + off + 4);
        xs[0] = x0.x; xs[1] = x0.y; xs[2] = x0.z; xs[3] = x0.w;
        xs[4] = x1.x; xs[5] = x1.y; xs[6] = x1.z; xs[7] = x1.w;
      }
      const int kst = kk >> 5, qd = (kk >> 3) & 3, j = kk & 7;
      const int d0 = dg * 8;
#pragma unroll
      for (int u = 0; u < 8; ++u) {
        const int d = d0 + u;
        kvbuf[((((d >> 4) * 3 + kst) * 64) + qd * 16 + (d & 15)) * 8 + j] =
            (f16)xs[u];
      }
    }
    __syncthreads();

    if (tid < 64) {
      float s2 = 0.f;
#pragma unroll
      for (int p = 0; p < 4; ++p) s2 += red[p * 64 + tid];
      l_run += s2;  // l = alpha*l_old + rowsum (alpha applied above)
    }

    // ---- GEMM2: O = alpha*O + P*V ----
    const floatx4 af = *(const floatx4*)&alphas[wave * 16 + quad * 4];
#pragma unroll
    for (int u = 0; u < 8; ++u) oacc[u] *= af;
#pragma unroll
    for (int ks = 0; ks < 3; ++ks) {
      const half8 a = *(const half8*)&pbuf[(((wave * 3 + ks) * 64) + lane) * 8];
#pragma unroll
      for (int u = 0; u < 8; ++u) {
        const half8 b =
            *(const half8*)&kvbuf[(((u * 3 + ks) * 64) + lane) * 8];
        oacc[u] = __builtin_amdgcn_mfma_f32_16x16x32_f16(a, b, oacc[u], 0, 0, 0);
      }
    }
  }

  // ---- epilogue: O / l, write out ----
  __syncthreads();
  if (tid < 64) mnew[tid] = 1.f / l_run;  // reuse mnew as linv
  __syncthreads();
  const floatx4 lf = *(const floatx4*)&mnew[wave * 16 + quad * 4];
#pragma unroll
  for (int r = 0; r < 4; ++r) {
    const int q = wave * 16 + quad * 4 + r;
    const size_t off =
        goff(t0 + (q >> 5), h0 + ((q >> 3) & 3), w0 + (q & 7), head);
#pragma unroll
    for (int u = 0; u < 8; ++u)
      op[off + u * 16 + ln] = oacc[u][r] * lf[r];
  }
}

}  // namespace

extern "C" void kernel_launch(void* const* d_in, const int* in_sizes, int n_in,
                              void* d_out, int out_size, void* d_ws,
                              size_t ws_size, hipStream_t stream) {
  const float* q = (const float*)d_in[0];
  const float* k = (const float*)d_in[1];
  const float* v = (const float*)d_in[2];
  float* out = (float*)d_out;
  const int nblocks = NH * (T / QT) * (H / QH) * (W / QW);  // 2048
  na3d_mfma<<<dim3(nblocks), dim3(256), 0, stream>>>(q, k, v, out);
}

// Round 3
// 528.502 us; speedup vs baseline: 1.0931x; 1.0931x over previous
//
#include <hip/hip_runtime.h>

// NATTEN 3D neighborhood attention — fp16 MFMA flash-style.
// B=1, T=16, H=32, W=32, nh=8, D=128, window (3,7,7), fp32 in/out.
//
// R6: LDS bank-conflict elimination (R5 profile: 1.24e8 conflict cycles
// = 45% of all CU-cycles).
//  - Padded frag-slot geometry: qd-stride 16->17 slots, tile-stride
//    64->69 slots (slot = 16B). Breaks the mod-128B aliasing that made
//    V b16-scatters 32-way and K/Q b128 staging writes 8-way conflicted.
//    Frag reads remain contiguous per 8-lane phase (conflict-free).
//  - pbuf: softmax pass 2 accumulates 8 consecutive-k P values into a
//    half8 and writes ONE b128 (was 24 scattered b16, 8-way).
// Structure otherwise = R5: 64 queries/block (2,4,8), 8 chunks of
// (1,5,14)=70 keys, online softmax, GEMM1 S^T=Q*K^T, GEMM2 O+=P*V.
// LDS ~77.9 KB -> 2 blocks/CU.

typedef _Float16 f16;
typedef _Float16 half8 __attribute__((ext_vector_type(8)));
typedef float floatx4 __attribute__((ext_vector_type(4)));

namespace {

constexpr int T = 16, H = 32, W = 32, NH = 8, D = 128;
constexpr int QT = 2, QH = 4, QW = 8;  // 64 queries/block
constexpr float SCALE = 0.088388347648318447f;  // 128^-0.5

// padded frag-slot index (units of 16B slots): tile stride 69, qd stride 17
__device__ __forceinline__ int SLOT(int tile, int lr) {
  return tile * 69 + (lr >> 4) * 17 + (lr & 15);
}

__device__ __forceinline__ size_t goff(int tt, int hh, int ww, int head) {
  return ((size_t)((tt * H + hh) * W + ww) * NH + head) * D;
}

__global__ __launch_bounds__(256) void na3d_mfma(
    const float* __restrict__ qp, const float* __restrict__ kp,
    const float* __restrict__ vp, float* __restrict__ op) {
  __shared__ alignas(16) f16 qbuf[16 * 69 * 8];   // Q  A-frags  17664 B
  __shared__ alignas(16) f16 kvbuf[24 * 69 * 8];  // K/V B-frags 26496 B
  __shared__ alignas(16) float st[80 * 65];       // S^T [key][q] 20800 B
  __shared__ alignas(16) f16 pbuf[12 * 69 * 8];   // P  A-frags  13248 B
  __shared__ alignas(16) float red[4 * 64];       // max/sum partials
  __shared__ alignas(16) float mnew[64];          // row max (then 1/l)
  __shared__ alignas(16) float alphas[64];        // rescale factors

  int bid = blockIdx.x;
  const int wb = bid & 3;  bid >>= 2;   // W/QW = 4
  const int hb = bid & 7;  bid >>= 3;   // H/QH = 8
  const int tb = bid & 7;  bid >>= 3;   // T/QT = 8
  const int head = bid;                 // 8

  const int t0 = tb * QT;
  const int h0 = hb * QH, w0 = wb * QW;
  const int bT = min(max(t0 - 1, 0), T - 4);    // key block T start (span 4)
  const int bH = min(max(h0 - 3, 0), H - 10);
  const int bW = min(max(w0 - 3, 0), W - 14);

  const int tid = threadIdx.x;
  const int wave = tid >> 6, lane = tid & 63;
  const int quad = lane >> 4, ln = lane & 15;

  // ---- Q staging: frag-order, pre-scaled, fp32->fp16 ----
  for (int s = tid; s < 1024; s += 256) {
    const int q = s >> 4, dg = s & 15;
    const size_t off =
        goff(t0 + (q >> 5), h0 + ((q >> 3) & 3), w0 + (q & 7), head) + dg * 8;
    const float4 x0 = *(const float4*)(qp + off);
    const float4 x1 = *(const float4*)(qp + off + 4);
    half8 hv;
    hv[0] = (f16)(x0.x * SCALE); hv[1] = (f16)(x0.y * SCALE);
    hv[2] = (f16)(x0.z * SCALE); hv[3] = (f16)(x0.w * SCALE);
    hv[4] = (f16)(x1.x * SCALE); hv[5] = (f16)(x1.y * SCALE);
    hv[6] = (f16)(x1.z * SCALE); hv[7] = (f16)(x1.w * SCALE);
    const int mt = q >> 4, m = q & 15, ks = dg >> 2, qd = dg & 3;
    *(half8*)&qbuf[SLOT(mt * 4 + ks, qd * 16 + m) * 8] = hv;
  }

  floatx4 oacc[8] = {{0.f, 0.f, 0.f, 0.f}, {0.f, 0.f, 0.f, 0.f},
                     {0.f, 0.f, 0.f, 0.f}, {0.f, 0.f, 0.f, 0.f},
                     {0.f, 0.f, 0.f, 0.f}, {0.f, 0.f, 0.f, 0.f},
                     {0.f, 0.f, 0.f, 0.f}, {0.f, 0.f, 0.f, 0.f}};
  // GEMM2: wave owns m-tile = wave (16 queries), all 8 d-groups (u)

  float m_run = -1e30f, l_run = 0.f;  // live in tid<64 only

  // softmax thread mapping: sq = query (0..63), sp = key-partition (0..3)
  const int sq = tid & 63, sp = tid >> 6;
  const int aT = min(max(t0 + (sq >> 5) - 1, 0), T - 3) - bT;         // 0..2
  const int aH = min(max(h0 + ((sq >> 3) & 3) - 3, 0), H - 7) - bH;   // 0..3
  const int aW = min(max(w0 + (sq & 7) - 3, 0), W - 7) - bW;          // 0..7

  for (int c = 0; c < 8; ++c) {
    const int dt = c >> 1, hh = c & 1;
    const int tt = bT + dt;
    const int kh0 = bH + hh * 5;
    const bool tOK = (dt >= aT) && (dt < aT + 3);  // per-query T-window

    __syncthreads();  // protect kvbuf from prior GEMM2 reads
    // ---- K staging: frag-order (rows are contiguous dims -> 16B copies) --
    for (int s = tid; s < 1120; s += 256) {
      const int kk = s >> 4, dg = s & 15;
      const int khl = kk / 14, kw = kk - khl * 14;
      const size_t off = goff(tt, kh0 + khl, bW + kw, head) + dg * 8;
      const float4 x0 = *(const float4*)(kp + off);
      const float4 x1 = *(const float4*)(kp + off + 4);
      half8 hv;
      hv[0] = (f16)x0.x; hv[1] = (f16)x0.y; hv[2] = (f16)x0.z; hv[3] = (f16)x0.w;
      hv[4] = (f16)x1.x; hv[5] = (f16)x1.y; hv[6] = (f16)x1.z; hv[7] = (f16)x1.w;
      const int nt = kk >> 4, n = kk & 15, ks = dg >> 2, qd = dg & 3;
      *(half8*)&kvbuf[SLOT(nt * 4 + ks, qd * 16 + n) * 8] = hv;
    }
    __syncthreads();

    // ---- GEMM1: S^T = Q * K^T (20 tiles = 4 mt x 5 nt over 4 waves) ----
    for (int tile = wave; tile < 20; tile += 4) {
      const int mt = tile / 5, nt = tile - mt * 5;
      floatx4 acc = {0.f, 0.f, 0.f, 0.f};
#pragma unroll
      for (int ks = 0; ks < 4; ++ks) {
        const half8 a = *(const half8*)&qbuf[SLOT(mt * 4 + ks, lane) * 8];
        const half8 b = *(const half8*)&kvbuf[SLOT(nt * 4 + ks, lane) * 8];
        acc = __builtin_amdgcn_mfma_f32_16x16x32_f16(a, b, acc, 0, 0, 0);
      }
      // D layout: col(lane&15)=key-within-tile, row(quad*4+reg)=query
      float* dst = &st[(nt * 16 + ln) * 65 + mt * 16 + quad * 4];
      dst[0] = acc[0]; dst[1] = acc[1]; dst[2] = acc[2]; dst[3] = acc[3];
    }
    __syncthreads();

    // ---- softmax pass 1: chunk row max (valid window only) ----
    float pm = -1e30f;
    if (tOK) {
#pragma unroll
      for (int i = 0; i < 18; ++i) {
        const int kk = sp * 18 + i;
        if (kk < 70) {
          const int khl = kk / 14, kw = kk - khl * 14;
          const int kha = hh * 5 + khl;
          if (kha >= aH && kha < aH + 7 && kw >= aW && kw < aW + 7)
            pm = fmaxf(pm, st[kk * 65 + sq]);
        }
      }
    }
    red[sp * 64 + sq] = pm;
    __syncthreads();
    if (tid < 64) {
      float mc = red[tid];
#pragma unroll
      for (int p = 1; p < 4; ++p) mc = fmaxf(mc, red[p * 64 + tid]);
      const float mN = fmaxf(m_run, mc);
      const float a = __expf(m_run - mN);
      m_run = mN; l_run *= a;
      mnew[tid] = mN; alphas[tid] = a;
    }
    __syncthreads();

    // ---- pass 2: P = exp(S-m); 8 consecutive-k values -> one b128 ----
    {
      const float mq = mnew[sq];
      float ps = 0.f;
      const int mt = sq >> 4, m = sq & 15;
#pragma unroll
      for (int g = 0; g < 3; ++g) {
        const int b = sp * 3 + g;          // k-block 0..11
        const int kst = b >> 2, qd = b & 3;
        half8 pv8;
#pragma unroll
        for (int j = 0; j < 8; ++j) {
          const int kk = b * 8 + j;
          float e = 0.f;
          if (tOK && kk < 70) {
            const int khl = kk / 14, kw = kk - khl * 14;
            const int kha = hh * 5 + khl;
            if (kha >= aH && kha < aH + 7 && kw >= aW && kw < aW + 7) {
              e = __expf(st[kk * 65 + sq] - mq);
              ps += e;
            }
          }
          pv8[j] = (f16)e;
        }
        *(half8*)&pbuf[SLOT(mt * 3 + kst, qd * 16 + m) * 8] = pv8;
      }
      red[sp * 64 + sq] = ps;
    }

    // ---- V staging: transpose into B-frag order (b16 scatters, padded
    // geometry -> <=4-way instead of 32-way). keys 70..95 ZEROED. ----
    for (int s = tid; s < 1536; s += 256) {
      const int kk = s >> 4, dg = s & 15;
      float xs[8] = {0.f, 0.f, 0.f, 0.f, 0.f, 0.f, 0.f, 0.f};
      if (kk < 70) {
        const int khl = kk / 14, kw = kk - khl * 14;
        const size_t off = goff(tt, kh0 + khl, bW + kw, head) + dg * 8;
        const float4 x0 = *(const float4*)(vp + off);
        const float4 x1 = *(const float4*)(vp + off + 4);
        xs[0] = x0.x; xs[1] = x0.y; xs[2] = x0.z; xs[3] = x0.w;
        xs[4] = x1.x; xs[5] = x1.y; xs[6] = x1.z; xs[7] = x1.w;
      }
      const int kst = kk >> 5, qd = (kk >> 3) & 3, j = kk & 7;
      const int d0 = dg * 8;
#pragma unroll
      for (int u = 0; u < 8; ++u) {
        const int d = d0 + u;
        kvbuf[SLOT((d >> 4) * 3 + kst, qd * 16 + (d & 15)) * 8 + j] =
            (f16)xs[u];
      }
    }
    __syncthreads();

    if (tid < 64) {
      float s2 = 0.f;
#pragma unroll
      for (int p = 0; p < 4; ++p) s2 += red[p * 64 + tid];
      l_run += s2;  // l = alpha*l_old + rowsum (alpha applied above)
    }

    // ---- GEMM2: O = alpha*O + P*V ----
    const floatx4 af = *(const floatx4*)&alphas[wave * 16 + quad * 4];
#pragma unroll
    for (int u = 0; u < 8; ++u) oacc[u] *= af;
#pragma unroll
    for (int ks = 0; ks < 3; ++ks) {
      const half8 a = *(const half8*)&pbuf[SLOT(wave * 3 + ks, lane) * 8];
#pragma unroll
      for (int u = 0; u < 8; ++u) {
        const half8 b = *(const half8*)&kvbuf[SLOT(u * 3 + ks, lane) * 8];
        oacc[u] = __builtin_amdgcn_mfma_f32_16x16x32_f16(a, b, oacc[u], 0, 0, 0);
      }
    }
  }

  // ---- epilogue: O / l, write out ----
  __syncthreads();
  if (tid < 64) mnew[tid] = 1.f / l_run;  // reuse mnew as linv
  __syncthreads();
  const floatx4 lf = *(const floatx4*)&mnew[wave * 16 + quad * 4];
#pragma unroll
  for (int r = 0; r < 4; ++r) {
    const int q = wave * 16 + quad * 4 + r;
    const size_t off =
        goff(t0 + (q >> 5), h0 + ((q >> 3) & 3), w0 + (q & 7), head);
#pragma unroll
    for (int u = 0; u < 8; ++u)
      op[off + u * 16 + ln] = oacc[u][r] * lf[r];
  }
}

}  // namespace

extern "C" void kernel_launch(void* const* d_in, const int* in_sizes, int n_in,
                              void* d_out, int out_size, void* d_ws,
                              size_t ws_size, hipStream_t stream) {
  const float* q = (const float*)d_in[0];
  const float* k = (const float*)d_in[1];
  const float* v = (const float*)d_in[2];
  float* out = (float*)d_out;
  const int nblocks = NH * (T / QT) * (H / QH) * (W / QW);  // 2048
  na3d_mfma<<<dim3(nblocks), dim3(256), 0, stream>>>(q, k, v, out);
}

// Round 5
// 496.509 us; speedup vs baseline: 1.1635x; 1.0644x over previous
//
#include <hip/hip_runtime.h>

// NATTEN 3D neighborhood attention — fp16 MFMA flash-style.
// B=1, T=16, H=32, W=32, nh=8, D=128, window (3,7,7), fp32 in/out.
//
// R7 (resubmit; infra failed): wave-private softmax via swapped GEMM1 +
// register prefetch pipeline.
//  - GEMM1 computes mfma(A=K_frag, B=Q_frag) -> D[m=key][n=query]:
//    lane&15 = query, so softmax is register-local per wave (2 shfl_xor
//    reduces). st/qbuf LDS buffers eliminated; 6 -> 4 barriers/chunk.
//  - Q frags live in 16 VGPRs (loaded once per block).
//  - P: 5 packed b64 writes to wave-private pbuf (lgkmcnt only, no barrier).
//  - Prefetch: V global loads issued at chunk top (hide under GEMM1);
//    K(c+1) loads issued after V-write (hide under softmax+GEMM2).
//    Raw s_barrier + explicit lgkmcnt(0) so prefetch isn't drained.
//  - V staging: key-pair packed b32 writes (24 vs 48 b16).
// LDS: kvbuf 26.5KB + pbuf 13.2KB = 39.7KB -> 3 blocks/CU (12 waves).
// Structure: 64 queries/block (2,4,8), 8 chunks of (1,5,14)=70 keys
// (padded to 80/96), online softmax, GEMM2 O += P*V unchanged.

typedef _Float16 f16;
typedef _Float16 half8 __attribute__((ext_vector_type(8)));
typedef _Float16 half4 __attribute__((ext_vector_type(4)));
typedef _Float16 half2 __attribute__((ext_vector_type(2)));
typedef float floatx4 __attribute__((ext_vector_type(4)));
typedef float floatv4 __attribute__((ext_vector_type(4)));

#define CFENCE() asm volatile("" ::: "memory")
#define BAR_PLAIN() do { CFENCE(); __builtin_amdgcn_s_barrier(); CFENCE(); } while (0)
#define BAR_LDSW() do { asm volatile("s_waitcnt lgkmcnt(0)" ::: "memory"); \
                        __builtin_amdgcn_s_barrier(); CFENCE(); } while (0)

namespace {

constexpr int T = 16, H = 32, W = 32, NH = 8, D = 128;
constexpr int QT = 2, QH = 4, QW = 8;  // 64 queries/block
constexpr float SCALE = 0.088388347648318447f;  // 128^-0.5

// padded frag-slot index (units of 16B slots): tile stride 69, qd stride 17
__device__ __forceinline__ int SLOT(int tile, int lr) {
  return tile * 69 + (lr >> 4) * 17 + (lr & 15);
}

__device__ __forceinline__ size_t goff(int tt, int hh, int ww, int head) {
  return ((size_t)((tt * H + hh) * W + ww) * NH + head) * D;
}

// exact floor(x/14) for 0 <= x < 96
__device__ __forceinline__ int div14(int x) { return (x * 586) >> 13; }

__global__ __launch_bounds__(256, 3) void na3d_mfma(
    const float* __restrict__ qp, const float* __restrict__ kp,
    const float* __restrict__ vp, float* __restrict__ op) {
  __shared__ alignas(16) f16 kvbuf[24 * 69 * 8];  // K/V frags 26496 B
  __shared__ alignas(16) f16 pbuf[12 * 69 * 8];   // P A-frags  13248 B

  int bid = blockIdx.x;
  const int wb = bid & 3;  bid >>= 2;   // W/QW = 4
  const int hb = bid & 7;  bid >>= 3;   // H/QH = 8
  const int tb = bid & 7;  bid >>= 3;   // T/QT = 8
  const int head = bid;                 // 8

  const int t0 = tb * QT;
  const int h0 = hb * QH, w0 = wb * QW;
  const int bT = min(max(t0 - 1, 0), T - 4);    // key block T start (span 4)
  const int bH = min(max(h0 - 3, 0), H - 10);
  const int bW = min(max(w0 - 3, 0), W - 14);

  const int tid = threadIdx.x;
  const int wave = tid >> 6, lane = tid & 63;
  const int quad = lane >> 4, ln = lane & 15;
  const int kbase = quad * 4;

  // per-lane query (wave w owns queries w*16 .. w*16+15; lane's q^ = ln)
  const int toff = wave >> 1;
  const int hoff = (wave & 1) * 2 + (ln >> 3);
  const int woff = ln & 7;
  const int aT = min(max(t0 + toff - 1, 0), T - 3) - bT;   // 0..2
  const int aH = min(max(h0 + hoff - 3, 0), H - 7) - bH;   // 0..3
  const int aW = min(max(w0 + woff - 3, 0), W - 7) - bW;   // 0..7

  // ---- Q fragments in registers (B-operand: row n = ln = query) ----
  half8 qreg[4];
  {
    const size_t row = goff(t0 + toff, h0 + hoff, w0 + woff, head);
#pragma unroll
    for (int ks = 0; ks < 4; ++ks) {
      const int d0 = ks * 32 + quad * 8;
      const floatv4 x0 = *(const floatv4*)(qp + row + d0);
      const floatv4 x1 = *(const floatv4*)(qp + row + d0 + 4);
      half8 hv;
      hv[0] = (f16)(x0[0] * SCALE); hv[1] = (f16)(x0[1] * SCALE);
      hv[2] = (f16)(x0[2] * SCALE); hv[3] = (f16)(x0[3] * SCALE);
      hv[4] = (f16)(x1[0] * SCALE); hv[5] = (f16)(x1[1] * SCALE);
      hv[6] = (f16)(x1[2] * SCALE); hv[7] = (f16)(x1[3] * SCALE);
      qreg[ks] = hv;
    }
  }

  // zero never-written pbuf region (keys 80..95: tile wave*3+2, groups 2,3)
  if (quad >= 2) {
    *(floatx4*)&pbuf[SLOT(wave * 3 + 2, lane) * 8] = (floatx4){0.f, 0.f, 0.f, 0.f};
  }

  floatx4 oacc[8] = {{0.f, 0.f, 0.f, 0.f}, {0.f, 0.f, 0.f, 0.f},
                     {0.f, 0.f, 0.f, 0.f}, {0.f, 0.f, 0.f, 0.f},
                     {0.f, 0.f, 0.f, 0.f}, {0.f, 0.f, 0.f, 0.f},
                     {0.f, 0.f, 0.f, 0.f}, {0.f, 0.f, 0.f, 0.f}};
  float m_run = -1e30f, l_run = 0.f;  // per lane, for query q^ = ln

  floatv4 kreg[5][2];  // K prefetch (chunk c+1)
  floatv4 vreg[3][4];  // V prefetch (chunk c)

  // ---- K prefetch for chunk 0 ----
  {
    const int tt = bT, kh0 = bH;
#pragma unroll
    for (int it = 0; it < 5; ++it) {
      const int s = tid + it * 256;
      if (s < 1120) {
        const int kk = s >> 4, dg = s & 15;
        const int khl = div14(kk), kw = kk - khl * 14;
        const size_t off = goff(tt, kh0 + khl, bW + kw, head) + dg * 8;
        kreg[it][0] = *(const floatv4*)(kp + off);
        kreg[it][1] = *(const floatv4*)(kp + off + 4);
      }
    }
  }

  for (int c = 0; c < 8; ++c) {
    const int dt = c >> 1;
    const int tt = bT + dt;
    const int kh0 = bH + (c & 1) * 5;
    const int hh5 = (c & 1) * 5;
    const bool tOK = (dt >= aT) && (dt < aT + 3);

    // ---- barrier A: all waves done with kvbuf V reads (GEMM2 of c-1) ----
    BAR_PLAIN();

    // ---- K LDS write from kreg (frag-order b128) ----
#pragma unroll
    for (int it = 0; it < 5; ++it) {
      const int s = tid + it * 256;
      if (s < 1120) {
        const int kk = s >> 4, dg = s & 15;
        const floatv4 a0 = kreg[it][0], a1 = kreg[it][1];
        half8 hv;
        hv[0] = (f16)a0[0]; hv[1] = (f16)a0[1];
        hv[2] = (f16)a0[2]; hv[3] = (f16)a0[3];
        hv[4] = (f16)a1[0]; hv[5] = (f16)a1[1];
        hv[6] = (f16)a1[2]; hv[7] = (f16)a1[3];
        *(half8*)&kvbuf[SLOT((kk >> 4) * 4 + (dg >> 2),
                             (dg & 3) * 16 + (kk & 15)) * 8] = hv;
      }
    }

    // ---- issue V global loads for chunk c (consumed after barrier C) ----
#pragma unroll
    for (int it = 0; it < 3; ++it) {
      const int s = tid + it * 256;
      const int p = s >> 4, dg = s & 15;
      const int kk0 = p * 2;
      if (kk0 < 70) {
        const int khl = div14(kk0), kw = kk0 - khl * 14;
        const size_t off = goff(tt, kh0 + khl, bW + kw, head) + dg * 8;
        vreg[it][0] = *(const floatv4*)(vp + off);
        vreg[it][1] = *(const floatv4*)(vp + off + 4);
        vreg[it][2] = *(const floatv4*)(vp + off + 1024);   // key kk0+1
        vreg[it][3] = *(const floatv4*)(vp + off + 1028);
      } else {
        vreg[it][0] = (floatv4){0.f, 0.f, 0.f, 0.f};
        vreg[it][1] = (floatv4){0.f, 0.f, 0.f, 0.f};
        vreg[it][2] = (floatv4){0.f, 0.f, 0.f, 0.f};
        vreg[it][3] = (floatv4){0.f, 0.f, 0.f, 0.f};
      }
    }

    // ---- barrier B: K visible (wait own LDS writes, not vmcnt) ----
    BAR_LDSW();

    // ---- GEMM1 (swapped): acc1[kt] = S^T[key][query] ----
    floatx4 acc1[5] = {{0.f, 0.f, 0.f, 0.f}, {0.f, 0.f, 0.f, 0.f},
                       {0.f, 0.f, 0.f, 0.f}, {0.f, 0.f, 0.f, 0.f},
                       {0.f, 0.f, 0.f, 0.f}};
#pragma unroll
    for (int kt = 0; kt < 5; ++kt) {
#pragma unroll
      for (int ks = 0; ks < 4; ++ks) {
        const half8 a = *(const half8*)&kvbuf[SLOT(kt * 4 + ks, lane) * 8];
        acc1[kt] =
            __builtin_amdgcn_mfma_f32_16x16x32_f16(a, qreg[ks], acc1[kt], 0, 0, 0);
      }
    }

    // ---- barrier C: all waves done reading K from kvbuf ----
    BAR_PLAIN();

    // ---- V LDS write from vreg (key-pair packed b32 scatters) ----
#pragma unroll
    for (int it = 0; it < 3; ++it) {
      const int s = tid + it * 256;
      const int p = s >> 4, dg = s & 15;
      const int kk0 = p * 2;
      const int kst = kk0 >> 5, qd = (kk0 >> 3) & 3, j0 = kk0 & 7;
      const int tbase = (dg >> 1) * 3 + kst;
      const int lrb = qd * 16 + (dg & 1) * 8;
#pragma unroll
      for (int u = 0; u < 8; ++u) {
        half2 h;
        h[0] = (f16)vreg[it][u >> 2][u & 3];
        h[1] = (f16)vreg[it][2 + (u >> 2)][u & 3];
        *(half2*)&kvbuf[SLOT(tbase, lrb + u) * 8 + j0] = h;
      }
    }

    // ---- issue K global loads for chunk c+1 ----
    if (c < 7) {
      const int cc = c + 1;
      const int ttn = bT + (cc >> 1);
      const int kh0n = bH + (cc & 1) * 5;
#pragma unroll
      for (int it = 0; it < 5; ++it) {
        const int s = tid + it * 256;
        if (s < 1120) {
          const int kk = s >> 4, dg = s & 15;
          const int khl = div14(kk), kw = kk - khl * 14;
          const size_t off = goff(ttn, kh0n + khl, bW + kw, head) + dg * 8;
          kreg[it][0] = *(const floatv4*)(kp + off);
          kreg[it][1] = *(const floatv4*)(kp + off + 4);
        }
      }
    }

    // ---- wave-private softmax (register-local; q^ = ln per lane) ----
    float pm = -1e30f;
#pragma unroll
    for (int kt = 0; kt < 5; ++kt) {
#pragma unroll
      for (int r = 0; r < 4; ++r) {
        const int kk = kt * 16 + kbase + r;
        const int khl = div14(kk), kw = kk - khl * 14;
        const int kha = hh5 + khl;
        const bool ok = tOK && (kk < 70) && ((unsigned)(kha - aH) < 7u) &&
                        ((unsigned)(kw - aW) < 7u);
        const float sv = ok ? acc1[kt][r] : -INFINITY;
        acc1[kt][r] = sv;
        pm = fmaxf(pm, sv);
      }
    }
    pm = fmaxf(pm, __shfl_xor(pm, 16));
    pm = fmaxf(pm, __shfl_xor(pm, 32));
    const float mN = fmaxf(m_run, pm);
    const float alpha = __expf(m_run - mN);
    m_run = mN;

    float ps = 0.f;
#pragma unroll
    for (int kt = 0; kt < 5; ++kt) {
      half4 h;
#pragma unroll
      for (int r = 0; r < 4; ++r) {
        const float e = __expf(acc1[kt][r] - mN);  // -inf -> 0
        ps += e;
        h[r] = (f16)e;
      }
      *(half4*)&pbuf[SLOT(wave * 3 + (kt >> 1),
                          ((kt & 1) * 2 + (quad >> 1)) * 16 + ln) * 8 +
                     (quad & 1) * 4] = h;
    }
    ps += __shfl_xor(ps, 16);
    ps += __shfl_xor(ps, 32);
    l_run = l_run * alpha + ps;

    // ---- barrier D: V + P visible ----
    BAR_LDSW();
    __builtin_amdgcn_sched_barrier(0);

    // ---- GEMM2: O = alpha*O + P*V ----
    floatx4 af;
#pragma unroll
    for (int r = 0; r < 4; ++r) af[r] = __shfl(alpha, kbase + r);
#pragma unroll
    for (int u = 0; u < 8; ++u) oacc[u] *= af;
#pragma unroll
    for (int ks = 0; ks < 3; ++ks) {
      const half8 a = *(const half8*)&pbuf[SLOT(wave * 3 + ks, lane) * 8];
#pragma unroll
      for (int u = 0; u < 8; ++u) {
        const half8 b = *(const half8*)&kvbuf[SLOT(u * 3 + ks, lane) * 8];
        oacc[u] = __builtin_amdgcn_mfma_f32_16x16x32_f16(a, b, oacc[u], 0, 0, 0);
      }
    }
  }

  // ---- epilogue: O / l, write out ----
  const float linv = 1.f / l_run;
  floatx4 lf;
#pragma unroll
  for (int r = 0; r < 4; ++r) lf[r] = __shfl(linv, kbase + r);
#pragma unroll
  for (int r = 0; r < 4; ++r) {
    const int q = wave * 16 + quad * 4 + r;
    const size_t off =
        goff(t0 + (q >> 5), h0 + ((q >> 3) & 3), w0 + (q & 7), head);
#pragma unroll
    for (int u = 0; u < 8; ++u)
      op[off + u * 16 + ln] = oacc[u][r] * lf[r];
  }
}

}  // namespace

extern "C" void kernel_launch(void* const* d_in, const int* in_sizes, int n_in,
                              void* d_out, int out_size, void* d_ws,
                              size_t ws_size, hipStream_t stream) {
  const float* q = (const float*)d_in[0];
  const float* k = (const float*)d_in[1];
  const float* v = (const float*)d_in[2];
  float* out = (float*)d_out;
  const int nblocks = NH * (T / QT) * (H / QH) * (W / QW);  // 2048
  na3d_mfma<<<dim3(nblocks), dim3(256), 0, stream>>>(q, k, v, out);
}

// Round 6
// 457.880 us; speedup vs baseline: 1.2617x; 1.0844x over previous
//
#include <hip/hip_runtime.h>

// NATTEN 3D neighborhood attention — fp16 MFMA flash-style.
// B=1, T=16, H=32, W=32, nh=8, D=128, window (3,7,7), fp32 in/out.
//
// R8 = R7 + XCD-aware block swizzle (T1) + s_setprio around MFMA (T5).
//  - R7 profile: hbm_bytes 2x'd vs R6 (960MB fetch) because consecutive
//    blockIdx round-robins across 8 XCD L2s -> spatial halo overlap
//    (8.75x logical redundancy) lands cross-XCD and re-fetches HBM.
//  - Swizzle: logical = (bid&7)*256 + (bid>>3); each XCD owns one head
//    (K+V 16MB/head, concurrent window ~5-7MB vs 4MB L2).
//  - R7 core: swapped GEMM1 (mfma(K,Q) -> lane&15=query) makes softmax
//    wave-private (2 shfl_xor); Q frags in VGPRs; register prefetch of
//    K(c+1)/V(c) rides across raw s_barriers on vmcnt only.
// LDS: kvbuf 26.5KB + pbuf 13.2KB = 39.7KB -> 3 blocks/CU.
// Structure: 64 queries/block (2,4,8), 8 chunks of (1,5,14)=70 keys
// (padded to 80/96), online softmax, GEMM2 O += P*V.

typedef _Float16 f16;
typedef _Float16 half8 __attribute__((ext_vector_type(8)));
typedef _Float16 half4 __attribute__((ext_vector_type(4)));
typedef _Float16 half2 __attribute__((ext_vector_type(2)));
typedef float floatx4 __attribute__((ext_vector_type(4)));
typedef float floatv4 __attribute__((ext_vector_type(4)));

#define CFENCE() asm volatile("" ::: "memory")
#define BAR_PLAIN() do { CFENCE(); __builtin_amdgcn_s_barrier(); CFENCE(); } while (0)
#define BAR_LDSW() do { asm volatile("s_waitcnt lgkmcnt(0)" ::: "memory"); \
                        __builtin_amdgcn_s_barrier(); CFENCE(); } while (0)

namespace {

constexpr int T = 16, H = 32, W = 32, NH = 8, D = 128;
constexpr int QT = 2, QH = 4, QW = 8;  // 64 queries/block
constexpr float SCALE = 0.088388347648318447f;  // 128^-0.5

// padded frag-slot index (units of 16B slots): tile stride 69, qd stride 17
__device__ __forceinline__ int SLOT(int tile, int lr) {
  return tile * 69 + (lr >> 4) * 17 + (lr & 15);
}

__device__ __forceinline__ size_t goff(int tt, int hh, int ww, int head) {
  return ((size_t)((tt * H + hh) * W + ww) * NH + head) * D;
}

// exact floor(x/14) for 0 <= x < 96
__device__ __forceinline__ int div14(int x) { return (x * 586) >> 13; }

__global__ __launch_bounds__(256, 3) void na3d_mfma(
    const float* __restrict__ qp, const float* __restrict__ kp,
    const float* __restrict__ vp, float* __restrict__ op) {
  __shared__ alignas(16) f16 kvbuf[24 * 69 * 8];  // K/V frags 26496 B
  __shared__ alignas(16) f16 pbuf[12 * 69 * 8];   // P A-frags  13248 B

  // T1: XCD-aware swizzle. HW round-robins blockIdx%8 across XCDs; remap
  // so each XCD gets a contiguous logical range = one head (256 blocks).
  int bid = (int)(((blockIdx.x & 7) << 8) | (blockIdx.x >> 3));
  const int wb = bid & 3;  bid >>= 2;   // W/QW = 4
  const int hb = bid & 7;  bid >>= 3;   // H/QH = 8
  const int tb = bid & 7;  bid >>= 3;   // T/QT = 8
  const int head = bid;                 // 8

  const int t0 = tb * QT;
  const int h0 = hb * QH, w0 = wb * QW;
  const int bT = min(max(t0 - 1, 0), T - 4);    // key block T start (span 4)
  const int bH = min(max(h0 - 3, 0), H - 10);
  const int bW = min(max(w0 - 3, 0), W - 14);

  const int tid = threadIdx.x;
  const int wave = tid >> 6, lane = tid & 63;
  const int quad = lane >> 4, ln = lane & 15;
  const int kbase = quad * 4;

  // per-lane query (wave w owns queries w*16 .. w*16+15; lane's q^ = ln)
  const int toff = wave >> 1;
  const int hoff = (wave & 1) * 2 + (ln >> 3);
  const int woff = ln & 7;
  const int aT = min(max(t0 + toff - 1, 0), T - 3) - bT;   // 0..2
  const int aH = min(max(h0 + hoff - 3, 0), H - 7) - bH;   // 0..3
  const int aW = min(max(w0 + woff - 3, 0), W - 7) - bW;   // 0..7

  // ---- Q fragments in registers (B-operand: row n = ln = query) ----
  half8 qreg[4];
  {
    const size_t row = goff(t0 + toff, h0 + hoff, w0 + woff, head);
#pragma unroll
    for (int ks = 0; ks < 4; ++ks) {
      const int d0 = ks * 32 + quad * 8;
      const floatv4 x0 = *(const floatv4*)(qp + row + d0);
      const floatv4 x1 = *(const floatv4*)(qp + row + d0 + 4);
      half8 hv;
      hv[0] = (f16)(x0[0] * SCALE); hv[1] = (f16)(x0[1] * SCALE);
      hv[2] = (f16)(x0[2] * SCALE); hv[3] = (f16)(x0[3] * SCALE);
      hv[4] = (f16)(x1[0] * SCALE); hv[5] = (f16)(x1[1] * SCALE);
      hv[6] = (f16)(x1[2] * SCALE); hv[7] = (f16)(x1[3] * SCALE);
      qreg[ks] = hv;
    }
  }

  // zero never-written pbuf region (keys 80..95: tile wave*3+2, groups 2,3)
  if (quad >= 2) {
    *(floatx4*)&pbuf[SLOT(wave * 3 + 2, lane) * 8] = (floatx4){0.f, 0.f, 0.f, 0.f};
  }

  floatx4 oacc[8] = {{0.f, 0.f, 0.f, 0.f}, {0.f, 0.f, 0.f, 0.f},
                     {0.f, 0.f, 0.f, 0.f}, {0.f, 0.f, 0.f, 0.f},
                     {0.f, 0.f, 0.f, 0.f}, {0.f, 0.f, 0.f, 0.f},
                     {0.f, 0.f, 0.f, 0.f}, {0.f, 0.f, 0.f, 0.f}};
  float m_run = -1e30f, l_run = 0.f;  // per lane, for query q^ = ln

  floatv4 kreg[5][2];  // K prefetch (chunk c+1)
  floatv4 vreg[3][4];  // V prefetch (chunk c)

  // ---- K prefetch for chunk 0 ----
  {
    const int tt = bT, kh0 = bH;
#pragma unroll
    for (int it = 0; it < 5; ++it) {
      const int s = tid + it * 256;
      if (s < 1120) {
        const int kk = s >> 4, dg = s & 15;
        const int khl = div14(kk), kw = kk - khl * 14;
        const size_t off = goff(tt, kh0 + khl, bW + kw, head) + dg * 8;
        kreg[it][0] = *(const floatv4*)(kp + off);
        kreg[it][1] = *(const floatv4*)(kp + off + 4);
      }
    }
  }

  for (int c = 0; c < 8; ++c) {
    const int dt = c >> 1;
    const int tt = bT + dt;
    const int kh0 = bH + (c & 1) * 5;
    const int hh5 = (c & 1) * 5;
    const bool tOK = (dt >= aT) && (dt < aT + 3);

    // ---- barrier A: all waves done with kvbuf V reads (GEMM2 of c-1) ----
    BAR_PLAIN();

    // ---- K LDS write from kreg (frag-order b128) ----
#pragma unroll
    for (int it = 0; it < 5; ++it) {
      const int s = tid + it * 256;
      if (s < 1120) {
        const int kk = s >> 4, dg = s & 15;
        const floatv4 a0 = kreg[it][0], a1 = kreg[it][1];
        half8 hv;
        hv[0] = (f16)a0[0]; hv[1] = (f16)a0[1];
        hv[2] = (f16)a0[2]; hv[3] = (f16)a0[3];
        hv[4] = (f16)a1[0]; hv[5] = (f16)a1[1];
        hv[6] = (f16)a1[2]; hv[7] = (f16)a1[3];
        *(half8*)&kvbuf[SLOT((kk >> 4) * 4 + (dg >> 2),
                             (dg & 3) * 16 + (kk & 15)) * 8] = hv;
      }
    }

    // ---- issue V global loads for chunk c (consumed after barrier C) ----
#pragma unroll
    for (int it = 0; it < 3; ++it) {
      const int s = tid + it * 256;
      const int p = s >> 4, dg = s & 15;
      const int kk0 = p * 2;
      if (kk0 < 70) {
        const int khl = div14(kk0), kw = kk0 - khl * 14;
        const size_t off = goff(tt, kh0 + khl, bW + kw, head) + dg * 8;
        vreg[it][0] = *(const floatv4*)(vp + off);
        vreg[it][1] = *(const floatv4*)(vp + off + 4);
        vreg[it][2] = *(const floatv4*)(vp + off + 1024);   // key kk0+1
        vreg[it][3] = *(const floatv4*)(vp + off + 1028);
      } else {
        vreg[it][0] = (floatv4){0.f, 0.f, 0.f, 0.f};
        vreg[it][1] = (floatv4){0.f, 0.f, 0.f, 0.f};
        vreg[it][2] = (floatv4){0.f, 0.f, 0.f, 0.f};
        vreg[it][3] = (floatv4){0.f, 0.f, 0.f, 0.f};
      }
    }

    // ---- barrier B: K visible (wait own LDS writes, not vmcnt) ----
    BAR_LDSW();

    // ---- GEMM1 (swapped): acc1[kt] = S^T[key][query] ----
    floatx4 acc1[5] = {{0.f, 0.f, 0.f, 0.f}, {0.f, 0.f, 0.f, 0.f},
                       {0.f, 0.f, 0.f, 0.f}, {0.f, 0.f, 0.f, 0.f},
                       {0.f, 0.f, 0.f, 0.f}};
    __builtin_amdgcn_s_setprio(1);
#pragma unroll
    for (int kt = 0; kt < 5; ++kt) {
#pragma unroll
      for (int ks = 0; ks < 4; ++ks) {
        const half8 a = *(const half8*)&kvbuf[SLOT(kt * 4 + ks, lane) * 8];
        acc1[kt] =
            __builtin_amdgcn_mfma_f32_16x16x32_f16(a, qreg[ks], acc1[kt], 0, 0, 0);
      }
    }
    __builtin_amdgcn_s_setprio(0);

    // ---- barrier C: all waves done reading K from kvbuf ----
    BAR_PLAIN();

    // ---- V LDS write from vreg (key-pair packed b32 scatters) ----
#pragma unroll
    for (int it = 0; it < 3; ++it) {
      const int s = tid + it * 256;
      const int p = s >> 4, dg = s & 15;
      const int kk0 = p * 2;
      const int kst = kk0 >> 5, qd = (kk0 >> 3) & 3, j0 = kk0 & 7;
      const int tbase = (dg >> 1) * 3 + kst;
      const int lrb = qd * 16 + (dg & 1) * 8;
#pragma unroll
      for (int u = 0; u < 8; ++u) {
        half2 h;
        h[0] = (f16)vreg[it][u >> 2][u & 3];
        h[1] = (f16)vreg[it][2 + (u >> 2)][u & 3];
        *(half2*)&kvbuf[SLOT(tbase, lrb + u) * 8 + j0] = h;
      }
    }

    // ---- issue K global loads for chunk c+1 ----
    if (c < 7) {
      const int cc = c + 1;
      const int ttn = bT + (cc >> 1);
      const int kh0n = bH + (cc & 1) * 5;
#pragma unroll
      for (int it = 0; it < 5; ++it) {
        const int s = tid + it * 256;
        if (s < 1120) {
          const int kk = s >> 4, dg = s & 15;
          const int khl = div14(kk), kw = kk - khl * 14;
          const size_t off = goff(ttn, kh0n + khl, bW + kw, head) + dg * 8;
          kreg[it][0] = *(const floatv4*)(kp + off);
          kreg[it][1] = *(const floatv4*)(kp + off + 4);
        }
      }
    }

    // ---- wave-private softmax (register-local; q^ = ln per lane) ----
    float pm = -1e30f;
#pragma unroll
    for (int kt = 0; kt < 5; ++kt) {
#pragma unroll
      for (int r = 0; r < 4; ++r) {
        const int kk = kt * 16 + kbase + r;
        const int khl = div14(kk), kw = kk - khl * 14;
        const int kha = hh5 + khl;
        const bool ok = tOK && (kk < 70) && ((unsigned)(kha - aH) < 7u) &&
                        ((unsigned)(kw - aW) < 7u);
        const float sv = ok ? acc1[kt][r] : -INFINITY;
        acc1[kt][r] = sv;
        pm = fmaxf(pm, sv);
      }
    }
    pm = fmaxf(pm, __shfl_xor(pm, 16));
    pm = fmaxf(pm, __shfl_xor(pm, 32));
    const float mN = fmaxf(m_run, pm);
    const float alpha = __expf(m_run - mN);
    m_run = mN;

    float ps = 0.f;
#pragma unroll
    for (int kt = 0; kt < 5; ++kt) {
      half4 h;
#pragma unroll
      for (int r = 0; r < 4; ++r) {
        const float e = __expf(acc1[kt][r] - mN);  // -inf -> 0
        ps += e;
        h[r] = (f16)e;
      }
      *(half4*)&pbuf[SLOT(wave * 3 + (kt >> 1),
                          ((kt & 1) * 2 + (quad >> 1)) * 16 + ln) * 8 +
                     (quad & 1) * 4] = h;
    }
    ps += __shfl_xor(ps, 16);
    ps += __shfl_xor(ps, 32);
    l_run = l_run * alpha + ps;

    // ---- barrier D: V + P visible ----
    BAR_LDSW();
    __builtin_amdgcn_sched_barrier(0);

    // ---- GEMM2: O = alpha*O + P*V ----
    floatx4 af;
#pragma unroll
    for (int r = 0; r < 4; ++r) af[r] = __shfl(alpha, kbase + r);
#pragma unroll
    for (int u = 0; u < 8; ++u) oacc[u] *= af;
    __builtin_amdgcn_s_setprio(1);
#pragma unroll
    for (int ks = 0; ks < 3; ++ks) {
      const half8 a = *(const half8*)&pbuf[SLOT(wave * 3 + ks, lane) * 8];
#pragma unroll
      for (int u = 0; u < 8; ++u) {
        const half8 b = *(const half8*)&kvbuf[SLOT(u * 3 + ks, lane) * 8];
        oacc[u] = __builtin_amdgcn_mfma_f32_16x16x32_f16(a, b, oacc[u], 0, 0, 0);
      }
    }
    __builtin_amdgcn_s_setprio(0);
  }

  // ---- epilogue: O / l, write out ----
  const float linv = 1.f / l_run;
  floatx4 lf;
#pragma unroll
  for (int r = 0; r < 4; ++r) lf[r] = __shfl(linv, kbase + r);
#pragma unroll
  for (int r = 0; r < 4; ++r) {
    const int q = wave * 16 + quad * 4 + r;
    const size_t off =
        goff(t0 + (q >> 5), h0 + ((q >> 3) & 3), w0 + (q & 7), head);
#pragma unroll
    for (int u = 0; u < 8; ++u)
      op[off + u * 16 + ln] = oacc[u][r] * lf[r];
  }
}

}  // namespace

extern "C" void kernel_launch(void* const* d_in, const int* in_sizes, int n_in,
                              void* d_out, int out_size, void* d_ws,
                              size_t ws_size, hipStream_t stream) {
  const float* q = (const float*)d_in[0];
  const float* k = (const float*)d_in[1];
  const float* v = (const float*)d_in[2];
  float* out = (float*)d_out;
  const int nblocks = NH * (T / QT) * (H / QH) * (W / QW);  // 2048
  na3d_mfma<<<dim3(nblocks), dim3(256), 0, stream>>>(q, k, v, out);
}

// Round 7
// 456.644 us; speedup vs baseline: 1.2651x; 1.0027x over previous
//
#include <hip/hip_runtime.h>

// NATTEN 3D neighborhood attention — fp16 MFMA flash-style.
// B=1, T=16, H=32, W=32, nh=8, D=128, window (3,7,7), fp32 in/out.
//
// R9 = R8 + register-liveness fences to kill scratch spill.
//  - R8 profile: WRITE_SIZE 229MB vs 67MB ideal (= scratch spill; R6
//    without reg-prefetch wrote 65MB). Cause: scheduler hoists next
//    prefetch's global loads above the LDS writes that end the previous
//    prefetch array's live range -> kreg(40)+vreg(48) live together ->
//    pressure > 168-reg cap (launch_bounds(256,3)) -> spill.
//  - Fix: CFENCE + sched_barrier(0) at the two death/birth boundaries
//    (after K-LDS-write before V-issue; after V-LDS-write before K-issue).
//    Prefetch loads still overlap downward with GEMM/softmax.
//  - R8 core: XCD swizzle (one head per XCD), s_setprio around MFMA,
//    swapped GEMM1 (mfma(K,Q) -> lane&15=query, wave-private softmax),
//    Q frags in VGPRs, K(c+1)/V(c) register prefetch riding across raw
//    s_barriers on vmcnt only.
// LDS: kvbuf 26.5KB + pbuf 13.2KB = 39.7KB -> 3 blocks/CU.
// Structure: 64 queries/block (2,4,8), 8 chunks of (1,5,14)=70 keys
// (padded to 80/96), online softmax, GEMM2 O += P*V.

typedef _Float16 f16;
typedef _Float16 half8 __attribute__((ext_vector_type(8)));
typedef _Float16 half4 __attribute__((ext_vector_type(4)));
typedef _Float16 half2 __attribute__((ext_vector_type(2)));
typedef float floatx4 __attribute__((ext_vector_type(4)));
typedef float floatv4 __attribute__((ext_vector_type(4)));

#define CFENCE() asm volatile("" ::: "memory")
#define BAR_PLAIN() do { CFENCE(); __builtin_amdgcn_s_barrier(); CFENCE(); } while (0)
#define BAR_LDSW() do { asm volatile("s_waitcnt lgkmcnt(0)" ::: "memory"); \
                        __builtin_amdgcn_s_barrier(); CFENCE(); } while (0)
#define LIVE_FENCE() do { CFENCE(); __builtin_amdgcn_sched_barrier(0); } while (0)

namespace {

constexpr int T = 16, H = 32, W = 32, NH = 8, D = 128;
constexpr int QT = 2, QH = 4, QW = 8;  // 64 queries/block
constexpr float SCALE = 0.088388347648318447f;  // 128^-0.5

// padded frag-slot index (units of 16B slots): tile stride 69, qd stride 17
__device__ __forceinline__ int SLOT(int tile, int lr) {
  return tile * 69 + (lr >> 4) * 17 + (lr & 15);
}

__device__ __forceinline__ size_t goff(int tt, int hh, int ww, int head) {
  return ((size_t)((tt * H + hh) * W + ww) * NH + head) * D;
}

// exact floor(x/14) for 0 <= x < 96
__device__ __forceinline__ int div14(int x) { return (x * 586) >> 13; }

__global__ __launch_bounds__(256, 3) void na3d_mfma(
    const float* __restrict__ qp, const float* __restrict__ kp,
    const float* __restrict__ vp, float* __restrict__ op) {
  __shared__ alignas(16) f16 kvbuf[24 * 69 * 8];  // K/V frags 26496 B
  __shared__ alignas(16) f16 pbuf[12 * 69 * 8];   // P A-frags  13248 B

  // T1: XCD-aware swizzle. HW round-robins blockIdx%8 across XCDs; remap
  // so each XCD gets a contiguous logical range = one head (256 blocks).
  int bid = (int)(((blockIdx.x & 7) << 8) | (blockIdx.x >> 3));
  const int wb = bid & 3;  bid >>= 2;   // W/QW = 4
  const int hb = bid & 7;  bid >>= 3;   // H/QH = 8
  const int tb = bid & 7;  bid >>= 3;   // T/QT = 8
  const int head = bid;                 // 8

  const int t0 = tb * QT;
  const int h0 = hb * QH, w0 = wb * QW;
  const int bT = min(max(t0 - 1, 0), T - 4);    // key block T start (span 4)
  const int bH = min(max(h0 - 3, 0), H - 10);
  const int bW = min(max(w0 - 3, 0), W - 14);

  const int tid = threadIdx.x;
  const int wave = tid >> 6, lane = tid & 63;
  const int quad = lane >> 4, ln = lane & 15;
  const int kbase = quad * 4;

  // per-lane query (wave w owns queries w*16 .. w*16+15; lane's q^ = ln)
  const int toff = wave >> 1;
  const int hoff = (wave & 1) * 2 + (ln >> 3);
  const int woff = ln & 7;
  const int aT = min(max(t0 + toff - 1, 0), T - 3) - bT;   // 0..2
  const int aH = min(max(h0 + hoff - 3, 0), H - 7) - bH;   // 0..3
  const int aW = min(max(w0 + woff - 3, 0), W - 7) - bW;   // 0..7

  // ---- Q fragments in registers (B-operand: row n = ln = query) ----
  half8 qreg[4];
  {
    const size_t row = goff(t0 + toff, h0 + hoff, w0 + woff, head);
#pragma unroll
    for (int ks = 0; ks < 4; ++ks) {
      const int d0 = ks * 32 + quad * 8;
      const floatv4 x0 = *(const floatv4*)(qp + row + d0);
      const floatv4 x1 = *(const floatv4*)(qp + row + d0 + 4);
      half8 hv;
      hv[0] = (f16)(x0[0] * SCALE); hv[1] = (f16)(x0[1] * SCALE);
      hv[2] = (f16)(x0[2] * SCALE); hv[3] = (f16)(x0[3] * SCALE);
      hv[4] = (f16)(x1[0] * SCALE); hv[5] = (f16)(x1[1] * SCALE);
      hv[6] = (f16)(x1[2] * SCALE); hv[7] = (f16)(x1[3] * SCALE);
      qreg[ks] = hv;
    }
  }

  // zero never-written pbuf region (keys 80..95: tile wave*3+2, groups 2,3)
  if (quad >= 2) {
    *(floatx4*)&pbuf[SLOT(wave * 3 + 2, lane) * 8] = (floatx4){0.f, 0.f, 0.f, 0.f};
  }

  floatx4 oacc[8] = {{0.f, 0.f, 0.f, 0.f}, {0.f, 0.f, 0.f, 0.f},
                     {0.f, 0.f, 0.f, 0.f}, {0.f, 0.f, 0.f, 0.f},
                     {0.f, 0.f, 0.f, 0.f}, {0.f, 0.f, 0.f, 0.f},
                     {0.f, 0.f, 0.f, 0.f}, {0.f, 0.f, 0.f, 0.f}};
  float m_run = -1e30f, l_run = 0.f;  // per lane, for query q^ = ln

  floatv4 kreg[5][2];  // K prefetch (chunk c+1); dead between K-write & re-issue
  floatv4 vreg[3][4];  // V prefetch (chunk c);  dead between V-write & re-issue

  // ---- K prefetch for chunk 0 ----
  {
    const int tt = bT, kh0 = bH;
#pragma unroll
    for (int it = 0; it < 5; ++it) {
      const int s = tid + it * 256;
      if (s < 1120) {
        const int kk = s >> 4, dg = s & 15;
        const int khl = div14(kk), kw = kk - khl * 14;
        const size_t off = goff(tt, kh0 + khl, bW + kw, head) + dg * 8;
        kreg[it][0] = *(const floatv4*)(kp + off);
        kreg[it][1] = *(const floatv4*)(kp + off + 4);
      }
    }
  }

  for (int c = 0; c < 8; ++c) {
    const int dt = c >> 1;
    const int tt = bT + dt;
    const int kh0 = bH + (c & 1) * 5;
    const int hh5 = (c & 1) * 5;
    const bool tOK = (dt >= aT) && (dt < aT + 3);

    // ---- barrier A: all waves done with kvbuf V reads (GEMM2 of c-1) ----
    BAR_PLAIN();

    // ---- K LDS write from kreg (frag-order b128); kreg DIES here ----
#pragma unroll
    for (int it = 0; it < 5; ++it) {
      const int s = tid + it * 256;
      if (s < 1120) {
        const int kk = s >> 4, dg = s & 15;
        const floatv4 a0 = kreg[it][0], a1 = kreg[it][1];
        half8 hv;
        hv[0] = (f16)a0[0]; hv[1] = (f16)a0[1];
        hv[2] = (f16)a0[2]; hv[3] = (f16)a0[3];
        hv[4] = (f16)a1[0]; hv[5] = (f16)a1[1];
        hv[6] = (f16)a1[2]; hv[7] = (f16)a1[3];
        *(half8*)&kvbuf[SLOT((kk >> 4) * 4 + (dg >> 2),
                             (dg & 3) * 16 + (kk & 15)) * 8] = hv;
      }
    }
    // liveness fence: keep V-issue below kreg death (no kreg+vreg overlap)
    LIVE_FENCE();

    // ---- issue V global loads for chunk c (consumed after barrier C) ----
#pragma unroll
    for (int it = 0; it < 3; ++it) {
      const int s = tid + it * 256;
      const int p = s >> 4, dg = s & 15;
      const int kk0 = p * 2;
      if (kk0 < 70) {
        const int khl = div14(kk0), kw = kk0 - khl * 14;
        const size_t off = goff(tt, kh0 + khl, bW + kw, head) + dg * 8;
        vreg[it][0] = *(const floatv4*)(vp + off);
        vreg[it][1] = *(const floatv4*)(vp + off + 4);
        vreg[it][2] = *(const floatv4*)(vp + off + 1024);   // key kk0+1
        vreg[it][3] = *(const floatv4*)(vp + off + 1028);
      } else {
        vreg[it][0] = (floatv4){0.f, 0.f, 0.f, 0.f};
        vreg[it][1] = (floatv4){0.f, 0.f, 0.f, 0.f};
        vreg[it][2] = (floatv4){0.f, 0.f, 0.f, 0.f};
        vreg[it][3] = (floatv4){0.f, 0.f, 0.f, 0.f};
      }
    }

    // ---- barrier B: K visible (wait own LDS writes, not vmcnt) ----
    BAR_LDSW();

    // ---- GEMM1 (swapped): acc1[kt] = S^T[key][query] ----
    floatx4 acc1[5] = {{0.f, 0.f, 0.f, 0.f}, {0.f, 0.f, 0.f, 0.f},
                       {0.f, 0.f, 0.f, 0.f}, {0.f, 0.f, 0.f, 0.f},
                       {0.f, 0.f, 0.f, 0.f}};
    __builtin_amdgcn_s_setprio(1);
#pragma unroll
    for (int kt = 0; kt < 5; ++kt) {
#pragma unroll
      for (int ks = 0; ks < 4; ++ks) {
        const half8 a = *(const half8*)&kvbuf[SLOT(kt * 4 + ks, lane) * 8];
        acc1[kt] =
            __builtin_amdgcn_mfma_f32_16x16x32_f16(a, qreg[ks], acc1[kt], 0, 0, 0);
      }
    }
    __builtin_amdgcn_s_setprio(0);

    // ---- barrier C: all waves done reading K from kvbuf ----
    BAR_PLAIN();

    // ---- V LDS write from vreg (key-pair packed b32); vreg DIES here ----
#pragma unroll
    for (int it = 0; it < 3; ++it) {
      const int s = tid + it * 256;
      const int p = s >> 4, dg = s & 15;
      const int kk0 = p * 2;
      const int kst = kk0 >> 5, qd = (kk0 >> 3) & 3, j0 = kk0 & 7;
      const int tbase = (dg >> 1) * 3 + kst;
      const int lrb = qd * 16 + (dg & 1) * 8;
#pragma unroll
      for (int u = 0; u < 8; ++u) {
        half2 h;
        h[0] = (f16)vreg[it][u >> 2][u & 3];
        h[1] = (f16)vreg[it][2 + (u >> 2)][u & 3];
        *(half2*)&kvbuf[SLOT(tbase, lrb + u) * 8 + j0] = h;
      }
    }
    // liveness fence: keep K-issue below vreg death (no kreg+vreg overlap)
    LIVE_FENCE();

    // ---- issue K global loads for chunk c+1 ----
    if (c < 7) {
      const int cc = c + 1;
      const int ttn = bT + (cc >> 1);
      const int kh0n = bH + (cc & 1) * 5;
#pragma unroll
      for (int it = 0; it < 5; ++it) {
        const int s = tid + it * 256;
        if (s < 1120) {
          const int kk = s >> 4, dg = s & 15;
          const int khl = div14(kk), kw = kk - khl * 14;
          const size_t off = goff(ttn, kh0n + khl, bW + kw, head) + dg * 8;
          kreg[it][0] = *(const floatv4*)(kp + off);
          kreg[it][1] = *(const floatv4*)(kp + off + 4);
        }
      }
    }

    // ---- wave-private softmax (register-local; q^ = ln per lane) ----
    float pm = -1e30f;
#pragma unroll
    for (int kt = 0; kt < 5; ++kt) {
#pragma unroll
      for (int r = 0; r < 4; ++r) {
        const int kk = kt * 16 + kbase + r;
        const int khl = div14(kk), kw = kk - khl * 14;
        const int kha = hh5 + khl;
        const bool ok = tOK && (kk < 70) && ((unsigned)(kha - aH) < 7u) &&
                        ((unsigned)(kw - aW) < 7u);
        const float sv = ok ? acc1[kt][r] : -INFINITY;
        acc1[kt][r] = sv;
        pm = fmaxf(pm, sv);
      }
    }
    pm = fmaxf(pm, __shfl_xor(pm, 16));
    pm = fmaxf(pm, __shfl_xor(pm, 32));
    const float mN = fmaxf(m_run, pm);
    const float alpha = __expf(m_run - mN);
    m_run = mN;

    float ps = 0.f;
#pragma unroll
    for (int kt = 0; kt < 5; ++kt) {
      half4 h;
#pragma unroll
      for (int r = 0; r < 4; ++r) {
        const float e = __expf(acc1[kt][r] - mN);  // -inf -> 0
        ps += e;
        h[r] = (f16)e;
      }
      *(half4*)&pbuf[SLOT(wave * 3 + (kt >> 1),
                          ((kt & 1) * 2 + (quad >> 1)) * 16 + ln) * 8 +
                     (quad & 1) * 4] = h;
    }
    ps += __shfl_xor(ps, 16);
    ps += __shfl_xor(ps, 32);
    l_run = l_run * alpha + ps;

    // ---- barrier D: V + P visible ----
    BAR_LDSW();
    __builtin_amdgcn_sched_barrier(0);

    // ---- GEMM2: O = alpha*O + P*V ----
    floatx4 af;
#pragma unroll
    for (int r = 0; r < 4; ++r) af[r] = __shfl(alpha, kbase + r);
#pragma unroll
    for (int u = 0; u < 8; ++u) oacc[u] *= af;
    __builtin_amdgcn_s_setprio(1);
#pragma unroll
    for (int ks = 0; ks < 3; ++ks) {
      const half8 a = *(const half8*)&pbuf[SLOT(wave * 3 + ks, lane) * 8];
#pragma unroll
      for (int u = 0; u < 8; ++u) {
        const half8 b = *(const half8*)&kvbuf[SLOT(u * 3 + ks, lane) * 8];
        oacc[u] = __builtin_amdgcn_mfma_f32_16x16x32_f16(a, b, oacc[u], 0, 0, 0);
      }
    }
    __builtin_amdgcn_s_setprio(0);
  }

  // ---- epilogue: O / l, write out ----
  const float linv = 1.f / l_run;
  floatx4 lf;
#pragma unroll
  for (int r = 0; r < 4; ++r) lf[r] = __shfl(linv, kbase + r);
#pragma unroll
  for (int r = 0; r < 4; ++r) {
    const int q = wave * 16 + quad * 4 + r;
    const size_t off =
        goff(t0 + (q >> 5), h0 + ((q >> 3) & 3), w0 + (q & 7), head);
#pragma unroll
    for (int u = 0; u < 8; ++u)
      op[off + u * 16 + ln] = oacc[u][r] * lf[r];
  }
}

}  // namespace

extern "C" void kernel_launch(void* const* d_in, const int* in_sizes, int n_in,
                              void* d_out, int out_size, void* d_ws,
                              size_t ws_size, hipStream_t stream) {
  const float* q = (const float*)d_in[0];
  const float* k = (const float*)d_in[1];
  const float* v = (const float*)d_in[2];
  float* out = (float*)d_out;
  const int nblocks = NH * (T / QT) * (H / QH) * (W / QW);  // 2048
  na3d_mfma<<<dim3(nblocks), dim3(256), 0, stream>>>(q, k, v, out);
}